// Round 11
// baseline (62.463 us; speedup 1.0000x reference)
//
#include <hip/hip_runtime.h>

#define NB 8
#define CHW 6300
#define TT 500
#define OUT 128
#define NO 1024
#define NK32 200          // total k32 steps (padded: 6300 -> 6400)
#define KSPLIT 8
#define NKC (NK32/KSPLIT) // 25 k32 per block

typedef __attribute__((ext_vector_type(8))) _Float16 f16x8;
typedef __attribute__((ext_vector_type(4))) float f32x4;

// Raw workgroup barrier draining ONLY lgkmcnt (LDS writes), not vmcnt:
// keeps global-load prefetches in flight across the barrier.
__device__ __forceinline__ void wg_barrier_lgkm() {
    asm volatile("s_waitcnt lgkmcnt(0)" ::: "memory");
    __builtin_amdgcn_s_barrier();
}

// ---------------- Kernel 1: fused pack+transpose+convert+MFMA GEMM ----------------
// v[t][n][o] = sum_c W[o][c] * x[n][c][t].
// A = W fp32 read DIRECTLY (no packW kernel): per frag, 2x float4 loads, then
// hi = f16(w), lo = f16((w-hi)*2048) in-reg -- bitwise identical to the old
// packW+ALOAD path. x path: coalesced dwordx4 -> Ls -> TRANS -> Bs (f16).
// lgkm-only barriers keep XG prefetches in flight.
__global__ __launch_bounds__(256, 2) void gemm(const float* __restrict__ x,
                                               const float* __restrict__ W,
                                               float* __restrict__ vp) {
    const int L = blockIdx.x;                 // 0..511
    const int logical = (L & 7) * 64 + (L >> 3);
    const int tb = logical & 7;               // t-block (64 t)
    const int n  = (logical >> 3) & 7;        // batch
    const int ks = logical >> 6;              // k-split 0..7

    const int tid = threadIdx.x;
    const int wave = tid >> 6;
    const int lane = tid & 63;
    const int l15 = lane & 15;
    const int lg  = lane >> 4;                // 0..3
    const int rr  = lg;                       // staging row-within-4
    const int ch  = l15;                      // staging t-chunk (4 floats)
    const int k32_0 = ks * NKC;

    __shared__ float    Ls[2][32][65];        // raw fp32 x tiles (16.6KB)
    __shared__ _Float16 Bs[2][4][512];        // f16 B-fragments (8KB)

    const float* xn = x + (size_t)n * CHW * TT;
    const int toff = tb * 64 + ch * 4;        // t chunk base (float idx)
    const bool tbok = (tb < 7);               // tb==7: only ch<13 valid (t<500)

    f32x4 acc[2][4][2] = {};                  // [ofrag][tfrag][hl]
    f16x8 Ar0[2][2], Ar1[2][2];               // A dbuf [ofrag][hl]
    float4 sA[2], sB[2];                      // x staging reg sets (XG parity)
    const float4 f4z = make_float4(0.f, 0.f, 0.f, 0.f);

#define XG(set, it)                                                                \
    {                                                                              \
        _Pragma("unroll") for (int p_ = 0; p_ < 2; p_++) {                         \
            const int r_ = wave * 8 + p_ * 4 + rr;                                 \
            const int c_ = (k32_0 + (it)) * 32 + r_;                               \
            const bool v_ = (c_ < CHW) && (tbok || ch < 13);                       \
            set[p_] = v_ ? *(const float4*)(xn + (size_t)c_ * TT + toff) : f4z;    \
        }                                                                          \
    }

#define DSW(set, bufL)                                                             \
    {                                                                              \
        _Pragma("unroll") for (int p_ = 0; p_ < 2; p_++) {                         \
            const int r_ = wave * 8 + p_ * 4 + rr;                                 \
            Ls[bufL][r_][ch * 4 + 0] = set[p_].x;                                  \
            Ls[bufL][r_][ch * 4 + 1] = set[p_].y;                                  \
            Ls[bufL][r_][ch * 4 + 2] = set[p_].z;                                  \
            Ls[bufL][r_][ch * 4 + 3] = set[p_].w;                                  \
        }                                                                          \
    }

#define TRANS(bufL, bufB)                                                          \
    {                                                                              \
        float tv_[8];                                                              \
        _Pragma("unroll") for (int i = 0; i < 8; i++)                              \
            tv_[i] = Ls[bufL][lg * 8 + i][wave * 16 + l15];                        \
        union { _Float16 h[8]; uint4 u; } tc_;                                     \
        _Pragma("unroll") for (int i = 0; i < 8; i++)                              \
            tc_.h[i] = (_Float16)tv_[i];                                           \
        *(uint4*)&Bs[bufB][wave][lane * 8] = tc_.u;                                \
    }

// Direct-W fragment load + hi/lo split (replaces packW+ALOAD, same bits)
#define WLOAD(Ar, it)                                                              \
    {                                                                              \
        const int c_ = (k32_0 + (it)) * 32 + lg * 8;                               \
        _Pragma("unroll") for (int of = 0; of < 2; of++) {                         \
            const int o_ = (wave * 2 + of) * 16 + l15;                             \
            const float* wp_ = W + (size_t)o_ * CHW + c_;                          \
            float wv_[8];                                                          \
            if (c_ + 8 <= CHW) {                                                   \
                float4 a_ = *(const float4*)(wp_);                                 \
                float4 b_ = *(const float4*)(wp_ + 4);                             \
                wv_[0] = a_.x; wv_[1] = a_.y; wv_[2] = a_.z; wv_[3] = a_.w;        \
                wv_[4] = b_.x; wv_[5] = b_.y; wv_[6] = b_.z; wv_[7] = b_.w;        \
            } else {                                                               \
                _Pragma("unroll") for (int i = 0; i < 8; i++)                      \
                    wv_[i] = (c_ + i < CHW) ? wp_[i] : 0.f;                        \
            }                                                                      \
            union { _Float16 h[8]; f16x8 v; } hi_, lo_;                            \
            _Pragma("unroll") for (int i = 0; i < 8; i++) {                        \
                _Float16 h_ = (_Float16)wv_[i];                                    \
                hi_.h[i] = h_;                                                     \
                lo_.h[i] = (_Float16)((wv_[i] - (float)h_) * 2048.f);              \
            }                                                                      \
            Ar[of][0] = hi_.v;                                                     \
            Ar[of][1] = lo_.v;                                                     \
        }                                                                          \
    }

#define COMPUTE(buf, Ar)                                                           \
    {                                                                              \
        f16x8 bfr[4];                                                              \
        _Pragma("unroll") for (int tf = 0; tf < 4; tf++)                           \
            bfr[tf] = *(const f16x8*)&Bs[buf][tf][lane * 8];                       \
        _Pragma("unroll") for (int of = 0; of < 2; of++)                           \
            _Pragma("unroll") for (int tf = 0; tf < 4; tf++)                       \
                _Pragma("unroll") for (int hl = 0; hl < 2; hl++)                   \
                    acc[of][tf][hl] = __builtin_amdgcn_mfma_f32_16x16x32_f16(      \
                        Ar[of][hl], bfr[tf], acc[of][tf][hl], 0, 0, 0);            \
    }

    // prologue: tiles 0..3 in flight; Bs[0]=tile0, Ls[1]=tile1 ready after
    XG(sA, 0)
    XG(sB, 1)
    DSW(sA, 0)            // waits sA (one-time stall, counted)
    XG(sA, 2)
    wg_barrier_lgkm();    // Ls[0] (tile 0) visible
    TRANS(0, 0)           // Bs[0] = tile 0
    DSW(sB, 1)            // Ls[1] = tile 1
    XG(sB, 3)
    WLOAD(Ar0, 0)
    wg_barrier_lgkm();    // Bs[0], Ls[1] visible

    for (int p = 0; p < 12; ++p) {
        const int it = 2 * p;
        // even step (cur=0): sA carries tile it+2 -> Ls[0]; XG(it+4)->sA
        WLOAD(Ar1, it + 1)
        DSW(sA, 0)                       // tile it+2 (always valid: it<=22)
        if (p <= 10) { XG(sA, it + 4) }
        TRANS(1, 1)                      // Bs[1] = tile it+1
        COMPUTE(0, Ar0)
        wg_barrier_lgkm();
        // odd step (cur=1)
        WLOAD(Ar0, it + 2)
        if (p <= 10) { DSW(sB, 1) }      // tile it+3
        if (p <= 9)  { XG(sB, it + 5) }
        TRANS(0, 0)                      // Bs[0] = tile it+2
        COMPUTE(1, Ar1)
        wg_barrier_lgkm();
    }
    // tail: it = 24
    COMPUTE(0, Ar0)

    // epilogue: D layout col(l&15)=t, row=(l>>4)*4+r = o-within-frag
    const float inv = 1.f / 2048.f;
#pragma unroll
    for (int of = 0; of < 2; of++) {
        const int o0 = (wave * 2 + of) * 16 + lg * 4;
#pragma unroll
        for (int tf = 0; tf < 4; tf++) {
            const int t = tb * 64 + tf * 16 + l15;
            if (t < TT) {
                f32x4 vo;
#pragma unroll
                for (int r = 0; r < 4; r++)
                    vo[r] = acc[of][tf][0][r] + acc[of][tf][1][r] * inv;
                *(f32x4*)(vp + (((size_t)ks * TT + t) * NB + n) * OUT + o0) = vo;
            }
        }
    }
#undef XG
#undef DSW
#undef TRANS
#undef WLOAD
#undef COMPUTE
}

// ---------------- Kernel 2: wave-specialized alpha+spike scan, fused 8-partial ----
// 32 blocks x 512 thr, 32 chains/block (halves per-CU staging BW vs 16-block).
// Wave 0 (lanes 0-31): serial G/H recursion; waves 1-7: stage next slab with
// the 8-partial K-sum fused (fixed order, deterministic).
#define SCN_RA 0.9048374180359595f       // exp(-0.1)
#define SCN_RACA 0.24596031111569496f    // RA*CA = 0.1*e^0.9
#define SCN_RS 0.36787944117144233f      // exp(-1)
#define SCN_RSCS -20.0f                  // RS*CS (CS = -20e)
#define SCN_RSCS2 -40.0f                 // 2*RS*CS
#define SCN_RSRSCS -7.3575888234288467f  // RS*RS*CS
#define SCN_TH 10.0f

#define CHAIN_STEP(i)                                                   \
    {                                                                   \
        float ua = Aa;                                                  \
        float w = fmaf(SCN_RS, G, ua);                                  \
        float u = sp ? (w + SCN_RSCS) : w;                              \
        bool sn = (u >= SCN_TH);                                        \
        sbuf[i][lane] = sn ? 1.f : 0.f;                                 \
        float Gb = fmaf(SCN_RS, G, H);                                  \
        G = sp ? (Gb + SCN_RSCS2) : Gb;                                 \
        float Hb = SCN_RS * H;                                          \
        H = sp ? (Hb + SCN_RSRSCS) : Hb;                                \
        sp = sn;                                                        \
        Ba = fmaf(SCN_RA, Ba, SCN_RACA * vv[i]);                        \
        Aa = fmaf(SCN_RA, Aa, Ba);                                      \
    }

__global__ __launch_bounds__(512) void scanspike(const float* __restrict__ vp,
                                                 float* __restrict__ out) {
    const int tid = threadIdx.x;
    const int wave = tid >> 6;
    const int lane = tid & 63;
    const int l5 = lane & 31;
    const int rh = lane >> 5;                // row-half within a pair
    const int g0 = blockIdx.x * 32;          // 32 chains per block
    const int cn = g0 >> 7;                  // n (fixed per block: 32 | 128)
    const int co = (g0 & 127) + l5;          // o of this lane's chain

    __shared__ float vbuf[2][64][32];        // [buf][tloc][chain] 16KB
    __shared__ float sbuf[64][33];           // [tloc][chain+pad]

    // prologue: all 8 waves stage slab 0 (row pairs: lane-half picks row)
    for (int rp = wave; rp * 2 < 64; rp += 8) {
        int r = rp * 2 + rh;
        float a = 0.f;
#pragma unroll
        for (int k = 0; k < KSPLIT; k++)
            a += vp[(((size_t)k * TT + r) * NB + cn) * OUT + co];
        vbuf[0][r][l5] = a;
    }
    __syncthreads();

    float Aa = 0.f, Ba = 0.f, G = 0.f, H = 0.f;
    bool sp = false;

    for (int tb = 0; tb < 8; ++tb) {
        const int cur = tb & 1;
        const int t0 = tb * 64;
        const int cnt = (tb == 7) ? 52 : 64;

        if (wave == 0) {
            if (lane < 32) {
                if (cnt == 64) {
                    float vv[64];
#pragma unroll
                    for (int i = 0; i < 64; ++i) vv[i] = vbuf[cur][i][l5];
#pragma unroll
                    for (int i = 0; i < 64; ++i) CHAIN_STEP(i)
                } else {
                    float vv[52];
#pragma unroll
                    for (int i = 0; i < 52; ++i) vv[i] = vbuf[cur][i][l5];
#pragma unroll
                    for (int i = 0; i < 52; ++i) CHAIN_STEP(i)
                }
            }
        } else if (tb < 7) {
            const int nt0 = t0 + 64;
            const int ncnt = (tb == 6) ? 52 : 64;
            for (int rp = wave - 1; rp * 2 < ncnt; rp += 7) {
                int r = rp * 2 + rh;
                float a = 0.f;
#pragma unroll
                for (int k = 0; k < KSPLIT; k++)
                    a += vp[(((size_t)k * TT + nt0 + r) * NB + cn) * OUT + co];
                vbuf[cur ^ 1][r][l5] = a;
            }
        }
        __syncthreads();

        // flush: 8 waves x 4 chains each; lanes cover t (coalesced 256B)
#pragma unroll
        for (int j = 0; j < 4; ++j) {
            int cc = wave * 4 + j;
            int oo = (g0 & 127) + cc;
            if (lane < cnt)
                out[((size_t)cn * OUT + oo) * TT + t0 + lane] = sbuf[lane][cc];
        }
        __syncthreads();
    }
}

extern "C" void kernel_launch(void* const* d_in, const int* in_sizes, int n_in,
                              void* d_out, int out_size, void* d_ws, size_t ws_size,
                              hipStream_t stream) {
    const float* x = (const float*)d_in[0];   // [8,2,50,63,500] fp32
    const float* W = (const float*)d_in[1];   // [128,6300] fp32
    float* out = (float*)d_out;               // [8,128,1,1,500] fp32

    float* vp = (float*)d_ws;                 // 16,384,000 B partials

    gemm<<<512, 256, 0, stream>>>(x, W, vp);
    scanspike<<<32, 512, 0, stream>>>(vp, out);
}